// Round 8
// baseline (379.474 us; speedup 1.0000x reference)
//
#include <hip/hip_runtime.h>

typedef __bf16 bf16x8 __attribute__((ext_vector_type(8)));
typedef float  f32x4  __attribute__((ext_vector_type(4)));

#define TILE   16
#define HALO   22      // TILE + 6
#define KK     7
#define NCLASS 49
#define IMW    256
#define IMH    256
#define HW     65536   // 256*256
#define HH     484     // HALO*HALO
#define OMS    57      // om row stride (odd -> conflict-free; 49..56 stay zero)
#define KPW    56      // KP2 row stride (entries n=0..55, zero-padded past 48)

__device__ __forceinline__ unsigned pack2bf(float a, float b) {
    unsigned ua = __float_as_uint(a);
    unsigned ub = __float_as_uint(b);
    ua = (ua + 0x7fffu + ((ua >> 16) & 1u)) >> 16;          // RNE bf16 of a (low half)
    ub = (ub + 0x7fffu + ((ub >> 16) & 1u)) & 0xffff0000u;  // RNE bf16 of b (high half)
    return (ua & 0xffffu) | ub;
}

__global__ __launch_bounds__(256, 2)
void gtnet_kernel(const float* __restrict__ im_input,
                  const float* __restrict__ gt_motion,
                  const float* __restrict__ m_kernel,
                  float* __restrict__ out_pred,
                  float* __restrict__ out_mask)
{
    // omW: om accumulator, ROW-major om[px][n] stride 57 (RMW pairs at dword
    // offsets (0,1) and (7,8) -> ds_read2/write2; odd stride -> conflict-free).
    // Rows fully zeroed so n=49..56 read as 0 (padding for fragment loads).
    // Later reused as W[px*57 + t].
    __shared__ float omW[256 * OMS];                  // 58368 B
    __shared__ unsigned KP2[NCLASS * KPW];            // 10976 B  (K[n,s],K[n+1,s]) 2xbf16
    __shared__ float2 halo[HH];                       // 3872 B   (motion ay,ax; sentinel -8)
    __shared__ __align__(16) float iml4[HH * 4];      // 7744 B   im halo, [q][c], c<3
    // total 80960 B -> 2 blocks/CU

    const int tid  = threadIdx.x;
    const int lane = tid & 63, wv_id = tid >> 6;
    const int tx = tid & 15, ty = tid >> 4;
    const int x0 = blockIdx.x * TILE, y0 = blockIdx.y * TILE;
    const int b  = blockIdx.z;
    const int x = x0 + tx, y = y0 + ty;

    // ---------------- phase 1: staging ----------------
    // KP2[s][n] = packed (bf16(K[n,s]), bf16(K[n+1,s])); zero past n=48
    for (int i = tid; i < NCLASS * KPW; i += 256) {
        int s = i / KPW, n = i - s * KPW;
        float a  = (n < NCLASS)     ? m_kernel[n * NCLASS + s]       : 0.0f;
        float b2 = (n + 1 < NCLASS) ? m_kernel[(n + 1) * NCLASS + s] : 0.0f;
        KP2[i] = pack2bf(a, b2);
    }

    const float* mot_x = gt_motion + (size_t)b * 2 * HW;  // channel 0 -> ax
    const float* mot_y = mot_x + HW;                      // channel 1 -> ay
    for (int i = tid; i < HH; i += 256) {
        int hy = i / HALO, hx = i - hy * HALO;
        int gy = y0 - 3 + hy, gx = x0 - 3 + hx;
        float2 v;
        if (gy >= 0 && gy < IMH && gx >= 0 && gx < IMW) {
            int off = gy * IMW + gx;
            v.x = mot_y[off] + 3.0f;
            v.y = mot_x[off] + 3.0f;
        } else {
            v.x = -8.0f; v.y = -8.0f;
        }
        halo[i] = v;
    }

    const float* imP = im_input + ((size_t)b * 6 + 3) * HW;  // last 3 channels
    for (int i = tid; i < HH; i += 256) {
        int hy = i / HALO, hx = i - hy * HALO;
        int gy = y0 - 3 + hy, gx = x0 - 3 + hx;
        float4 v = {0.0f, 0.0f, 0.0f, 0.0f};
        if (gy >= 0 && gy < IMH && gx >= 0 && gx < IMW) {
            int off = gy * IMW + gx;
            v.x = imP[off];
            v.y = imP[off + HW];
            v.z = imP[off + 2 * HW];
        }
        *reinterpret_cast<float4*>(&iml4[i * 4]) = v;
    }

    {   // zero om (full rows incl. padding) via float2 stores
        float2* omv = reinterpret_cast<float2*>(omW);
        for (int i = tid; i < 256 * OMS / 2; i += 256) omv[i] = make_float2(0.0f, 0.0f);
    }

    __syncthreads();

    // ---------------- phase 2: m_mask dense write ----------------
    {
        float2 h = halo[(ty + 3) * HALO + (tx + 3)];
        float iyf = floorf(h.x), ixf = floorf(h.y);
        float fy = h.x - iyf,    fx = h.y - ixf;
        int   iy = (int)iyf,     ix = (int)ixf;
        float wyA[KK], wxB[KK];
        #pragma unroll
        for (int a = 0; a < KK; a++) {
            wyA[a] = (a == iy) ? (1.0f - fy) : ((a == iy + 1) ? fy : 0.0f);
            wxB[a] = (a == ix) ? (1.0f - fx) : ((a == ix + 1) ? fx : 0.0f);
        }
        float* mm = out_mask + (size_t)b * NCLASS * HW + y * IMW + x;
        #pragma unroll
        for (int a = 0; a < KK; a++)
            #pragma unroll
            for (int bb = 0; bb < KK; bb++)
                mm[(size_t)(a * KK + bb) * HW] = wyA[a] * wxB[bb];
    }

    // ---------------- phase 3: om scatter (row-major, paired RMW + packed K) -----
    float* const omRow = &omW[tid * OMS];
    #pragma unroll
    for (int u = 0; u < KK; u++) {
        #pragma unroll
        for (int v = 0; v < KK; v++) {
            const int s = u * KK + v;                  // compile-time
            float2 h = halo[(ty + u) * HALO + (tx + v)];
            float ayc = h.x, axc = h.y;
            float iyf = floorf(ayc), ixf = floorf(axc);
            float fy = ayc - iyf,    fx = axc - ixf;
            bool  valid = (ayc >= 0.0f);
            float wy0 = valid ? (1.0f - fy) : 0.0f;
            float wy1 = valid ? fy : 0.0f;
            int   n00 = valid ? ((int)iyf * KK + (int)ixf) : 0;
            unsigned pA = KP2[s * KPW + n00];          // (k00,k01) packed bf16
            unsigned pB = KP2[s * KPW + n00 + KK];     // (k10,k11) packed bf16
            float k00 = __uint_as_float(pA << 16);
            float k01 = __uint_as_float(pA & 0xffff0000u);
            float k10 = __uint_as_float(pB << 16);
            float k11 = __uint_as_float(pB & 0xffff0000u);
            float wx0 = 1.0f - fx;
            float* ob = omRow + n00;
            float o0 = ob[0], o1 = ob[1];              // ds_read2 (0,1)
            float o7 = ob[KK], o8 = ob[KK + 1];        // ds_read2 (7,8)
            ob[0]      = fmaf(wy0 * wx0, k00, o0);
            ob[1]      = fmaf(wy0 * fx , k01, o1);
            ob[KK]     = fmaf(wy1 * wx0, k10, o7);
            ob[KK + 1] = fmaf(wy1 * fx , k11, o8);
        }
    }

    __syncthreads();   // om complete

    // ---------------- phase 4: load MFMA fragments ----------------
    // A[m][k]: m=lane&15 (pixel in slab), k=(lane>>4)*8+j. k0=56 reads the zeroed
    // row padding (offset 49..56) -> zero frag, no branches.
    bf16x8 af[2][4];   // [kiter][mtile]
    #pragma unroll
    for (int kit = 0; kit < 2; kit++) {
        #pragma unroll
        for (int mt = 0; mt < 4; mt++) {
            int px  = wv_id * 64 + mt * 16 + (lane & 15);
            int k0  = kit * 32 + (lane >> 4) * 8;
            int k0r = (k0 > 48) ? 49 : k0;            // 49..56 are zeros
            const float* r = &omW[px * OMS + k0r];
            bf16x8 a;
            #pragma unroll
            for (int j = 0; j < 8; j++) a[j] = (__bf16)r[j];
            af[kit][mt] = a;
        }
    }
    // B[k][col]: col=lane&15 (t), k rows from KP2[t][n] pairs (n even steps)
    bf16x8 bfr[2][4];  // [kiter][ntile]
    #pragma unroll
    for (int kit = 0; kit < 2; kit++) {
        #pragma unroll
        for (int nt = 0; nt < 4; nt++) {
            int t   = nt * 16 + (lane & 15);
            int k0  = kit * 32 + (lane >> 4) * 8;
            int k0r = (k0 > 48) ? 49 : k0;            // entries >=49 are packed zeros
            union { unsigned u[4]; bf16x8 v; } bu;
            #pragma unroll
            for (int j = 0; j < 4; j++) bu.u[j] = KP2[t * KPW + k0r + 2 * j];
            bfr[kit][nt] = bu.v;
        }
    }

    __syncthreads();   // all om reads done before W overwrites the region

    // ---------------- phase 5: MFMA GEMM  W[256x49] = om[256x64] x K^T ----------
    f32x4 acc[4][4];
    #pragma unroll
    for (int mt = 0; mt < 4; mt++) {
        #pragma unroll
        for (int nt = 0; nt < 4; nt++) {
            f32x4 c = {0.0f, 0.0f, 0.0f, 0.0f};
            c = __builtin_amdgcn_mfma_f32_16x16x32_bf16(af[0][mt], bfr[0][nt], c, 0, 0, 0);
            c = __builtin_amdgcn_mfma_f32_16x16x32_bf16(af[1][mt], bfr[1][nt], c, 0, 0, 0);
            acc[mt][nt] = c;
        }
    }

    // writeback: C/D layout col=lane&15 (t), row=(lane>>4)*4+reg (px) -> W[px*57+t]
    #pragma unroll
    for (int mt = 0; mt < 4; mt++) {
        #pragma unroll
        for (int nt = 0; nt < 4; nt++) {
            int t = nt * 16 + (lane & 15);
            if (t < NCLASS) {
                #pragma unroll
                for (int r = 0; r < 4; r++) {
                    int px = wv_id * 64 + mt * 16 + (lane >> 4) * 4 + r;
                    omW[px * OMS + t] = acc[mt][nt][r];
                }
            }
        }
    }

    __syncthreads();   // W complete

    // ---------------- phase 6: apply effective 7x7 kernel ----------------
    float wv[NCLASS];
    #pragma unroll
    for (int t = 0; t < NCLASS; t++) wv[t] = omW[tid * OMS + t];

    float a0 = 0.0f, a1 = 0.0f, a2 = 0.0f;
    #pragma unroll
    for (int p = 0; p < KK; p++) {
        #pragma unroll
        for (int q = 0; q < KK; q++) {
            float wvv = wv[p * KK + q];
            int   hi = (ty + p) * HALO + (tx + q);
            float4 im3 = *reinterpret_cast<const float4*>(&iml4[hi * 4]);  // ds_read_b128
            a0 = fmaf(wvv, im3.x, a0);
            a1 = fmaf(wvv, im3.y, a1);
            a2 = fmaf(wvv, im3.z, a2);
        }
    }
    float* pr = out_pred + (size_t)b * 3 * HW + y * IMW + x;
    pr[0]      = a0;
    pr[HW]     = a1;
    pr[2 * HW] = a2;
}

extern "C" void kernel_launch(void* const* d_in, const int* in_sizes, int n_in,
                              void* d_out, int out_size, void* d_ws, size_t ws_size,
                              hipStream_t stream) {
    const float* im_input  = (const float*)d_in[0];
    // d_in[1] = im_output: unused by the reference computation
    const float* gt_motion = (const float*)d_in[2];
    const float* m_kernel  = (const float*)d_in[3];

    float* pred = (float*)d_out;                        // (16,3,256,256)
    float* mask = pred + (size_t)16 * 3 * HW;           // (16,49,256,256)

    dim3 grid(IMW / TILE, IMH / TILE, 16);
    dim3 block(256);
    hipLaunchKernelGGL(gtnet_kernel, grid, block, 0, stream,
                       im_input, gt_motion, m_kernel, pred, mask);
}

// Round 9
// 356.671 us; speedup vs baseline: 1.0639x; 1.0639x over previous
//
#include <hip/hip_runtime.h>
#include <hip/hip_fp16.h>

typedef _Float16 f16x8 __attribute__((ext_vector_type(8)));
typedef float    f32x4 __attribute__((ext_vector_type(4)));

#define TILE   16
#define HALO   22      // TILE + 6
#define KK     7
#define NCLASS 49
#define IMW    256
#define IMH    256
#define HW     65536   // 256*256
#define HH     484     // HALO*HALO
#define WST    52      // W row stride (f32, 208 B -> 16B-aligned rows)

__device__ __forceinline__ unsigned h2u(__half2 h) { union { __half2 h; unsigned u; } c; c.h = h; return c.u; }
__device__ __forceinline__ __half2  u2h(unsigned u) { union { __half2 h; unsigned u; } c; c.u = u; return c.h; }
// om pair-row for class n: even n -> E-row n/2 (pairs (2r,2r+1), rows 0..24);
// odd n -> O-row 25+(n>>1) (pairs (2r+1,2r+2), rows 25..48). Low half = smaller class.
__device__ __forceinline__ int rowOf(int n) { return (n & 1) ? (25 + (n >> 1)) : (n >> 1); }

__global__ __launch_bounds__(256, 2)
void gtnet_kernel(const float* __restrict__ im_input,
                  const float* __restrict__ gt_motion,
                  const float* __restrict__ m_kernel,
                  float* __restrict__ out_pred,
                  float* __restrict__ out_mask)
{
    // omP: fp16-pair om accumulator, class-pair-major [row][px] (bank = px%32,
    // conflict-free scatter; plain RMW, columns thread-private). Reused as f32
    // W[px][WST] after the MFMA. 256*52*4 = 53248 B covers both.
    __shared__ __align__(16) unsigned omP[256 * WST];
    __shared__ unsigned KB[NCLASS * NCLASS];   // 9604 B: KB[s][row] = packed f16 K-pair
    __shared__ uint4    haloP[HH];             // 7744 B: (wy01, wx0fx, rowA<<16|rowB, 0)
    __shared__ __align__(16) float iml4[HH * 4];  // 7744 B: im halo (c0,c1,c2,0)
    // total 78340 B -> 2 blocks/CU

    const int tid  = threadIdx.x;
    const int lane = tid & 63, wv_id = tid >> 6;
    const int tx = tid & 15, ty = tid >> 4;
    const int x0 = blockIdx.x * TILE, y0 = blockIdx.y * TILE;
    const int b  = blockIdx.z;
    const int x = x0 + tx, y = y0 + ty;

    // ---------------- phase 1: staging ----------------
    // KB[s*49 + row] = packed f16 (K[n0,s], K[n0+1,s]) for the row's class pair
    for (int i = tid; i < NCLASS * NCLASS; i += 256) {
        int s = i / NCLASS, r = i - s * NCLASS;
        int n0 = (r < 25) ? (2 * r) : (2 * (r - 25) + 1);
        int n1 = n0 + 1;
        float k0 = m_kernel[n0 * NCLASS + s];                       // n0 <= 48 always
        float k1 = (n1 < NCLASS) ? m_kernel[n1 * NCLASS + s] : 0.f; // row 24 high = 0
        KB[i] = h2u(__halves2half2(__float2half_rn(k0), __float2half_rn(k1)));
    }

    const float* mot_x = gt_motion + (size_t)b * 2 * HW;  // channel 0 -> ax
    const float* mot_y = mot_x + HW;                      // channel 1 -> ay
    for (int i = tid; i < HH; i += 256) {
        int hy = i / HALO, hx = i - hy * HALO;
        int gy = y0 - 3 + hy, gx = x0 - 3 + hx;
        uint4 e;
        if (gy >= 0 && gy < IMH && gx >= 0 && gx < IMW) {
            int off = gy * IMW + gx;
            float ay = mot_y[off] + 3.0f;
            float ax = mot_x[off] + 3.0f;
            float iyf = floorf(ay), ixf = floorf(ax);
            float fy = ay - iyf,    fx = ax - ixf;
            int   n00 = (int)iyf * KK + (int)ixf;
            e.x = h2u(__halves2half2(__float2half_rn(1.0f - fy), __float2half_rn(fy)));
            e.y = h2u(__halves2half2(__float2half_rn(1.0f - fx), __float2half_rn(fx)));
            e.z = (unsigned)((rowOf(n00) << 16) | rowOf(n00 + KK));
            e.w = 0;
        } else {
            e.x = 0; e.y = 0; e.z = (0u << 16) | 28u; e.w = 0;   // zero weights
        }
        haloP[i] = e;
    }

    const float* imP = im_input + ((size_t)b * 6 + 3) * HW;  // last 3 channels
    for (int i = tid; i < HH; i += 256) {
        int hy = i / HALO, hx = i - hy * HALO;
        int gy = y0 - 3 + hy, gx = x0 - 3 + hx;
        float4 v = {0.0f, 0.0f, 0.0f, 0.0f};
        if (gy >= 0 && gy < IMH && gx >= 0 && gx < IMW) {
            int off = gy * IMW + gx;
            v.x = imP[off];
            v.y = imP[off + HW];
            v.z = imP[off + 2 * HW];
        }
        *reinterpret_cast<float4*>(&iml4[i * 4]) = v;
    }

    {   // zero om pair-rows (49*256 dwords) via b128
        uint4* p = reinterpret_cast<uint4*>(omP);
        for (int i = tid; i < (NCLASS * 256) / 4 + 1; i += 256)
            if (i * 4 < NCLASS * 256 + 4) p[i] = make_uint4(0, 0, 0, 0);
    }

    __syncthreads();

    // ---------------- phase 2: m_mask dense write (exact f32, from global) -------
    {
        int off = y * IMW + x;
        float ay = mot_y[off] + 3.0f;
        float ax = mot_x[off] + 3.0f;
        float iyf = floorf(ay), ixf = floorf(ax);
        float fy = ay - iyf,    fx = ax - ixf;
        int   iy = (int)iyf,    ix = (int)ixf;
        float wyA[KK], wxB[KK];
        #pragma unroll
        for (int a = 0; a < KK; a++) {
            wyA[a] = (a == iy) ? (1.0f - fy) : ((a == iy + 1) ? fy : 0.0f);
            wxB[a] = (a == ix) ? (1.0f - fx) : ((a == ix + 1) ? fx : 0.0f);
        }
        float* mm = out_mask + (size_t)b * NCLASS * HW + off;
        #pragma unroll
        for (int a = 0; a < KK; a++)
            #pragma unroll
            for (int bb = 0; bb < KK; bb++)
                mm[(size_t)(a * KK + bb) * HW] = wyA[a] * wxB[bb];
    }

    // ---------------- phase 3: om scatter — 2 packed RMWs per tap ----------------
    #pragma unroll
    for (int u = 0; u < KK; u++) {
        #pragma unroll
        for (int v = 0; v < KK; v++) {
            const int s = u * KK + v;                  // compile-time
            uint4 hp = haloP[(ty + u) * HALO + (tx + v)];
            __half2 wy = u2h(hp.x);                    // (wy0, wy1)
            __half2 wx = u2h(hp.y);                    // (wx0, fx)
            int rowA = (int)(hp.z >> 16), rowB = (int)(hp.z & 0xffffu);
            __half2 kA = u2h(KB[s * NCLASS + rowA]);
            __half2 kB = u2h(KB[s * NCLASS + rowB]);
            __half2 cA = __hmul2(__hmul2(__low2half2(wy),  wx), kA);
            __half2 cB = __hmul2(__hmul2(__high2half2(wy), wx), kB);
            unsigned* pA = &omP[rowA * 256 + tid];
            unsigned* pB = &omP[rowB * 256 + tid];
            *pA = h2u(__hadd2(u2h(*pA), cA));
            *pB = h2u(__hadd2(u2h(*pB), cB));
        }
    }

    __syncthreads();   // om complete

    // ---------------- phase 4: assemble MFMA f16 fragments -----------------------
    // A[m][k]: m=lane&15 (px in slab), k=(lane>>4)*8+j. Packed dword i covers
    // classes (k0+2i, k0+2i+1): E-dword rE+i plus O parts via alignbit merge.
    f16x8 af[2][4];
    #pragma unroll
    for (int kit = 0; kit < 2; kit++) {
        #pragma unroll
        for (int mt = 0; mt < 4; mt++) {
            int kk0 = kit * 32 + (lane >> 4) * 8;
            int rE  = kk0 >> 1;
            int px  = wv_id * 64 + mt * 16 + (lane & 15);
            unsigned Ew[4], Ow[5];
            #pragma unroll
            for (int i2 = 0; i2 < 4; i2++) {
                int r = rE + i2;                       // <= 31, in-bounds
                unsigned val = omP[r * 256 + px];
                Ew[i2] = (r <= 24) ? val : 0u;
            }
            #pragma unroll
            for (int j = 0; j < 5; j++) {
                int o   = rE - 1 + j;                  // -1..31
                int row = 25 + o;
                row = (row > 48) ? 48 : row;           // clamp in-bounds (o=-1 -> 24, fine)
                unsigned val = omP[row * 256 + px];
                Ow[j] = (o >= 0 && o <= 23) ? val : 0u;
            }
            union { unsigned u[4]; f16x8 v; } au;
            #pragma unroll
            for (int i2 = 0; i2 < 4; i2++) {
                unsigned oal = (Ow[i2 + 1] << 16) | (Ow[i2] >> 16);
                au.u[i2] = h2u(__hadd2(u2h(Ew[i2]), u2h(oal)));
            }
            af[kit][mt] = au.v;
        }
    }
    // B[k][t]: packed dword j = (K[k0+2j,t], K[k0+2j+1,t]) = KB[t][rE+j] (E rows)
    f16x8 bfr[2][4];
    #pragma unroll
    for (int kit = 0; kit < 2; kit++) {
        #pragma unroll
        for (int nt = 0; nt < 4; nt++) {
            int t   = nt * 16 + (lane & 15);
            int kk0 = kit * 32 + (lane >> 4) * 8;
            int rE  = kk0 >> 1;
            union { unsigned u[4]; f16x8 v; } bu;
            #pragma unroll
            for (int j = 0; j < 4; j++) {
                int r = rE + j;                        // <= 31, in-bounds
                unsigned val = KB[t * NCLASS + r];
                bu.u[j] = (r <= 24) ? val : 0u;
            }
            bfr[kit][nt] = bu.v;
        }
    }

    __syncthreads();   // all om reads done before W overwrites the region

    // ---------------- phase 5: MFMA GEMM  W[256x49] = om x K^T -------------------
    f32x4 acc[4][4];
    #pragma unroll
    for (int mt = 0; mt < 4; mt++) {
        #pragma unroll
        for (int nt = 0; nt < 4; nt++) {
            f32x4 c = {0.0f, 0.0f, 0.0f, 0.0f};
            c = __builtin_amdgcn_mfma_f32_16x16x32_f16(af[0][mt], bfr[0][nt], c, 0, 0, 0);
            c = __builtin_amdgcn_mfma_f32_16x16x32_f16(af[1][mt], bfr[1][nt], c, 0, 0, 0);
            acc[mt][nt] = c;
        }
    }

    float* Wf = reinterpret_cast<float*>(omP);
    // C/D layout: col=lane&15 (t), row=(lane>>4)*4+reg (px) -> W[px*WST+t]
    #pragma unroll
    for (int mt = 0; mt < 4; mt++) {
        #pragma unroll
        for (int nt = 0; nt < 4; nt++) {
            int t = nt * 16 + (lane & 15);
            if (t < NCLASS) {
                #pragma unroll
                for (int r = 0; r < 4; r++) {
                    int px = wv_id * 64 + mt * 16 + (lane >> 4) * 4 + r;
                    Wf[px * WST + t] = acc[mt][nt][r];
                }
            }
        }
    }

    __syncthreads();   // W complete

    // ---------------- phase 6: apply effective 7x7 kernel ------------------------
    float wv[NCLASS];
    #pragma unroll
    for (int t = 0; t < NCLASS; t++) wv[t] = Wf[tid * WST + t];   // 13 x b128

    float a0 = 0.0f, a1 = 0.0f, a2 = 0.0f;
    #pragma unroll
    for (int p = 0; p < KK; p++) {
        #pragma unroll
        for (int q = 0; q < KK; q++) {
            float wvv = wv[p * KK + q];
            int   hi = (ty + p) * HALO + (tx + q);
            float4 im3 = *reinterpret_cast<const float4*>(&iml4[hi * 4]);  // b128
            a0 = fmaf(wvv, im3.x, a0);
            a1 = fmaf(wvv, im3.y, a1);
            a2 = fmaf(wvv, im3.z, a2);
        }
    }
    float* pr = out_pred + (size_t)b * 3 * HW + y * IMW + x;
    pr[0]      = a0;
    pr[HW]     = a1;
    pr[2 * HW] = a2;
}

extern "C" void kernel_launch(void* const* d_in, const int* in_sizes, int n_in,
                              void* d_out, int out_size, void* d_ws, size_t ws_size,
                              hipStream_t stream) {
    const float* im_input  = (const float*)d_in[0];
    // d_in[1] = im_output: unused by the reference computation
    const float* gt_motion = (const float*)d_in[2];
    const float* m_kernel  = (const float*)d_in[3];

    float* pred = (float*)d_out;                        // (16,3,256,256)
    float* mask = pred + (size_t)16 * 3 * HW;           // (16,49,256,256)

    dim3 grid(IMW / TILE, IMH / TILE, 16);
    dim3 block(256);
    hipLaunchKernelGGL(gtnet_kernel, grid, block, 0, stream,
                       im_input, gt_motion, m_kernel, pred, mask);
}

// Round 10
// 339.836 us; speedup vs baseline: 1.1166x; 1.0495x over previous
//
#include <hip/hip_runtime.h>
#include <hip/hip_fp16.h>

typedef _Float16 f16x8 __attribute__((ext_vector_type(8)));
typedef float    f32x4 __attribute__((ext_vector_type(4)));

#define TILE   16
#define HALO   22      // TILE + 6
#define KK     7
#define NCLASS 49
#define IMW    256
#define IMH    256
#define HW     65536   // 256*256
#define HH     484     // HALO*HALO
#define NV     42      // V-rows 0..41 (n00 <= 40)
#define WST    52      // W row stride (f32, 208 B -> 16B-aligned rows)

// LDS layout (dwords):
#define OFF_OMV    0        // 2 halves * 42 rows * 128 px          = 10752
#define OFF_HALOW  10752    // uint2[484]  (wyP, wxP)               =   968
#define OFF_HALON  11720    // uint [484]  n00*4                    =   484
#define OFF_KV     12204    // uint [49*42] vertical K pairs        =  2058
#define OFF_KE     14262    // uint [49*25] horizontal K pairs      =  1225
#define OFF_IML64  15488    // float2[484] im (c0,c1)  (8B aligned) =   968
#define OFF_IML32  16456    // float [484] im c2                    =   484
#define SH_TOTAL   16940    // 67760 B -> 2 blocks/CU

__device__ __forceinline__ unsigned h2u(__half2 h) { union { __half2 h; unsigned u; } c; c.h = h; return c.u; }
__device__ __forceinline__ __half2  u2h(unsigned u) { union { __half2 h; unsigned u; } c; c.u = u; return c.h; }

__global__ __launch_bounds__(256, 2)
void gtnet_kernel(const float* __restrict__ im_input,
                  const float* __restrict__ gt_motion,
                  const float* __restrict__ m_kernel,
                  float* __restrict__ out_pred,
                  float* __restrict__ out_mask)
{
    __shared__ __align__(16) unsigned SH[SH_TOTAL];
    unsigned* const omV   = SH + OFF_OMV;     // [half][v][128] packed (om[v], om[v+7])
    uint2*   const haloW  = (uint2*)(SH + OFF_HALOW);
    unsigned* const haloN = SH + OFF_HALON;
    unsigned* const KV    = SH + OFF_KV;      // KV[s*42+n] = (K[n,s], K[n+7,s]) f16x2
    unsigned* const KE    = SH + OFF_KE;      // KE[t*25+j] = (K[2j,t], K[2j+1,t]) f16x2
    float2*  const iml64  = (float2*)(SH + OFF_IML64);
    float*   const iml32  = (float*)(SH + OFF_IML32);
    float*   const Wf     = (float*)SH;       // overlays omV..KV after phase 5

    const int tid  = threadIdx.x;
    const int lane = tid & 63, wv_id = tid >> 6;
    const int tx = tid & 15, ty = tid >> 4;
    const int x0 = blockIdx.x * TILE, y0 = blockIdx.y * TILE;
    const int b  = blockIdx.z;
    const int x = x0 + tx, y = y0 + ty;

    // ---------------- phase 1: staging ----------------
    for (int i = tid; i < NCLASS * NV; i += 256) {      // KV
        int s = i / NV, n = i - s * NV;
        float k0 = m_kernel[n * NCLASS + s];
        float k7 = m_kernel[(n + KK) * NCLASS + s];     // n <= 41 -> n+7 <= 48
        KV[i] = h2u(__halves2half2(__float2half_rn(k0), __float2half_rn(k7)));
    }
    for (int i = tid; i < NCLASS * 25; i += 256) {      // KE
        int t = i / 25, j = i - t * 25;
        float k0 = m_kernel[(2 * j) * NCLASS + t];
        float k1 = (2 * j + 1 < NCLASS) ? m_kernel[(2 * j + 1) * NCLASS + t] : 0.0f;
        KE[i] = h2u(__halves2half2(__float2half_rn(k0), __float2half_rn(k1)));
    }

    const float* mot_x = gt_motion + (size_t)b * 2 * HW;  // channel 0 -> ax
    const float* mot_y = mot_x + HW;                      // channel 1 -> ay
    for (int i = tid; i < HH; i += 256) {
        int hy = i / HALO, hx = i - hy * HALO;
        int gy = y0 - 3 + hy, gx = x0 - 3 + hx;
        uint2 wv2 = make_uint2(0u, 0u);
        unsigned n4 = 0;
        if (gy >= 0 && gy < IMH && gx >= 0 && gx < IMW) {
            int off = gy * IMW + gx;
            float ay = mot_y[off] + 3.0f;
            float ax = mot_x[off] + 3.0f;
            float iyf = floorf(ay), ixf = floorf(ax);
            float fy = ay - iyf,    fx = ax - ixf;
            int n00 = (int)iyf * KK + (int)ixf;
            n00 = (n00 < 0) ? 0 : ((n00 > 40) ? 40 : n00);
            wv2.x = h2u(__halves2half2(__float2half_rn(1.0f - fy), __float2half_rn(fy)));
            wv2.y = h2u(__halves2half2(__float2half_rn(1.0f - fx), __float2half_rn(fx)));
            n4 = (unsigned)(n00 * 4);
        }
        haloW[i] = wv2;
        haloN[i] = n4;
    }

    const float* imP = im_input + ((size_t)b * 6 + 3) * HW;  // last 3 channels
    for (int i = tid; i < HH; i += 256) {
        int hy = i / HALO, hx = i - hy * HALO;
        int gy = y0 - 3 + hy, gx = x0 - 3 + hx;
        float2 v01 = make_float2(0.0f, 0.0f);
        float  v2  = 0.0f;
        if (gy >= 0 && gy < IMH && gx >= 0 && gx < IMW) {
            int off = gy * IMW + gx;
            v01.x = imP[off];
            v01.y = imP[off + HW];
            v2    = imP[off + 2 * HW];
        }
        iml64[i] = v01;
        iml32[i] = v2;
    }

    {   // zero omV (10752 dwords) via b128
        uint4* p = reinterpret_cast<uint4*>(omV);
        for (int i = tid; i < (2 * NV * 128) / 4; i += 256) p[i] = make_uint4(0, 0, 0, 0);
    }

    __syncthreads();

    // ---------------- phase 2: m_mask dense write (exact f32) ----------------
    {
        int off = y * IMW + x;
        float ay = mot_y[off] + 3.0f;
        float ax = mot_x[off] + 3.0f;
        float iyf = floorf(ay), ixf = floorf(ax);
        float fy = ay - iyf,    fx = ax - ixf;
        int   iy = (int)iyf,    ix = (int)ixf;
        float wyA[KK], wxB[KK];
        #pragma unroll
        for (int a = 0; a < KK; a++) {
            wyA[a] = (a == iy) ? (1.0f - fy) : ((a == iy + 1) ? fy : 0.0f);
            wxB[a] = (a == ix) ? (1.0f - fx) : ((a == ix + 1) ? fx : 0.0f);
        }
        float* mm = out_mask + (size_t)b * NCLASS * HW + off;
        #pragma unroll
        for (int a = 0; a < KK; a++)
            #pragma unroll
            for (int bb = 0; bb < KK; bb++)
                mm[(size_t)(a * KK + bb) * HW] = wyA[a] * wxB[bb];
    }

    // ---------------- phase 3: scatter — 1 read2 + 1 write2 per tap --------------
    // omHalf base for this thread's pixel column
    unsigned* const omHalf = omV + (tid >> 7) * (NV * 128) + (tid & 127);
    #pragma unroll
    for (int u = 0; u < KK; u++) {
        #pragma unroll
        for (int v = 0; v < KK; v++) {
            const int s = u * KK + v;                    // compile-time
            const int q = (ty + u) * HALO + (tx + v);
            uint2 wyx = haloW[q];                        // ds_read_b64
            unsigned n4 = haloN[q];                      // n00*4
            const unsigned* kp =
                (const unsigned*)((const char*)KV + s * (NV * 4) + n4);
            unsigned kvA = kp[0], kvB = kp[1];           // ds_read2_b32 (0,1)
            unsigned* ob = (unsigned*)((char*)omHalf + n4 * 128);  // n00*512 B
            unsigned o0 = ob[0], o1 = ob[128];           // ds_read2_b32 (0,128)
            __half2 wy = u2h(wyx.x), wx = u2h(wyx.y);
            __half2 cA = __hmul2(__hmul2(wy, __low2half2(wx)),  u2h(kvA));
            __half2 cB = __hmul2(__hmul2(wy, __high2half2(wx)), u2h(kvB));
            ob[0]   = h2u(__hadd2(u2h(o0), cA));         // ds_write2_b32 (0,128)
            ob[128] = h2u(__hadd2(u2h(o1), cB));
        }
    }

    __syncthreads();   // omV complete

    // ---------------- phase 4: assemble MFMA f16 fragments -----------------------
    // om[n] = lo(V[n]) + hi(V[n-7]).  A dword covers classes (c0, c0+1), c0 even.
    f16x8 af[2][4];
    #pragma unroll
    for (int kit = 0; kit < 2; kit++) {
        #pragma unroll
        for (int mt = 0; mt < 4; mt++) {
            int k0  = kit * 32 + (lane >> 4) * 8;
            int px  = wv_id * 64 + mt * 16 + (lane & 15);
            const unsigned* pxb = omV + (px >> 7) * (NV * 128) + (px & 127);
            union { unsigned u[4]; f16x8 v; } au;
            #pragma unroll
            for (int j = 0; j < 4; j++) {
                int c0 = k0 + 2 * j;                     // even
                // lo pair: V[c0], V[c0+1] (valid iff c0 <= 40)
                int rl = (c0 > 40) ? 40 : c0;
                unsigned d0 = pxb[rl * 128], d1 = pxb[rl * 128 + 128];  // read2
                unsigned loM = (d0 & 0xffffu) | (d1 << 16);
                loM = (c0 <= 40) ? loM : 0u;
                // hi: class c0 from V[c0-7], class c0+1 from V[c0-6] (independent)
                int r0 = c0 - 7; r0 = (r0 < 0) ? 0 : ((r0 > 41) ? 41 : r0);
                int r1 = c0 - 6; r1 = (r1 < 0) ? 0 : ((r1 > 41) ? 41 : r1);
                unsigned e0 = pxb[r0 * 128];
                unsigned e1 = pxb[r1 * 128];
                e0 = (c0 >= 8 && c0 <= 48) ? e0 : 0u;    // c0 even, >=8 covers c0-7>=0
                e1 = (c0 >= 6 && c0 <= 48) ? e1 : 0u;    // class c0+1 valid from c0=6
                unsigned hiM = (e0 >> 16) | (e1 & 0xffff0000u);
                au.u[j] = h2u(__hadd2(u2h(loM), u2h(hiM)));
            }
            af[kit][mt] = au.v;
        }
    }
    // B[k][t] dword j = (K[c0,t], K[c0+1,t]) = KE[t*25 + c0/2]
    f16x8 bfr[2][4];
    #pragma unroll
    for (int kit = 0; kit < 2; kit++) {
        #pragma unroll
        for (int nt = 0; nt < 4; nt++) {
            int t  = nt * 16 + (lane & 15);
            int k0 = kit * 32 + (lane >> 4) * 8;
            union { unsigned u[4]; f16x8 v; } bu;
            #pragma unroll
            for (int j = 0; j < 4; j++) {
                int c0 = k0 + 2 * j;
                int j2 = c0 >> 1;
                unsigned val = KE[t * 25 + ((j2 > 24) ? 24 : j2)];
                bu.u[j] = (c0 <= 48) ? val : 0u;
            }
            bfr[kit][nt] = bu.v;
        }
    }

    __syncthreads();   // all omV/KV/KE reads done before W overwrites the region

    // ---------------- phase 5: MFMA GEMM  W[256x49] = om x K^T -------------------
    f32x4 acc[4][4];
    #pragma unroll
    for (int mt = 0; mt < 4; mt++) {
        #pragma unroll
        for (int nt = 0; nt < 4; nt++) {
            f32x4 c = {0.0f, 0.0f, 0.0f, 0.0f};
            c = __builtin_amdgcn_mfma_f32_16x16x32_f16(af[0][mt], bfr[0][nt], c, 0, 0, 0);
            c = __builtin_amdgcn_mfma_f32_16x16x32_f16(af[1][mt], bfr[1][nt], c, 0, 0, 0);
            acc[mt][nt] = c;
        }
    }

    // C/D layout: col=lane&15 (t), row=(lane>>4)*4+reg (px) -> W[px*WST+t]
    #pragma unroll
    for (int mt = 0; mt < 4; mt++) {
        #pragma unroll
        for (int nt = 0; nt < 4; nt++) {
            int t = nt * 16 + (lane & 15);
            if (t < NCLASS) {
                #pragma unroll
                for (int r = 0; r < 4; r++) {
                    int px = wv_id * 64 + mt * 16 + (lane >> 4) * 4 + r;
                    Wf[px * WST + t] = acc[mt][nt][r];
                }
            }
        }
    }

    __syncthreads();   // W complete

    // ---------------- phase 6: apply effective 7x7 kernel ------------------------
    float wv[NCLASS];
    #pragma unroll
    for (int t = 0; t < NCLASS; t++) wv[t] = Wf[tid * WST + t];   // 13 x b128

    float a0 = 0.0f, a1 = 0.0f, a2 = 0.0f;
    #pragma unroll
    for (int p = 0; p < KK; p++) {
        #pragma unroll
        for (int q = 0; q < KK; q++) {
            float wvv = wv[p * KK + q];
            int   hi = (ty + p) * HALO + (tx + q);
            float2 i01 = iml64[hi];                      // ds_read_b64
            float  i2  = iml32[hi];                      // ds_read_b32
            a0 = fmaf(wvv, i01.x, a0);
            a1 = fmaf(wvv, i01.y, a1);
            a2 = fmaf(wvv, i2,    a2);
        }
    }
    float* pr = out_pred + (size_t)b * 3 * HW + y * IMW + x;
    pr[0]      = a0;
    pr[HW]     = a1;
    pr[2 * HW] = a2;
}

extern "C" void kernel_launch(void* const* d_in, const int* in_sizes, int n_in,
                              void* d_out, int out_size, void* d_ws, size_t ws_size,
                              hipStream_t stream) {
    const float* im_input  = (const float*)d_in[0];
    // d_in[1] = im_output: unused by the reference computation
    const float* gt_motion = (const float*)d_in[2];
    const float* m_kernel  = (const float*)d_in[3];

    float* pred = (float*)d_out;                        // (16,3,256,256)
    float* mask = pred + (size_t)16 * 3 * HW;           // (16,49,256,256)

    dim3 grid(IMW / TILE, IMH / TILE, 16);
    dim3 block(256);
    hipLaunchKernelGGL(gtnet_kernel, grid, block, 0, stream,
                       im_input, gt_motion, m_kernel, pred, mask);
}